// Round 19
// baseline (402.573 us; speedup 1.0000x reference)
//
#include <hip/hip_runtime.h>

// ArcMarginLoss fused: normalize -> MX-fp4 MFMA GEMM + fixed-max softmax -> NLL mean.
// N=8192, D=512, C=32000, scale=16, margin=0.2.
// R19: 32x32x64 fp4 shape (9099 TF ubench vs 7228 for 16x16x128): 21% fewer MFMA
// issue cyc/FLOP and 2x FLOP/instruction halves all per-instr overhead per FLOP.
// Per-lane one-scale-block property holds (k in [ks*64+(lane>>5)*32,+32)) -> same
// opsel-byte scheme R15 validated. Splits padded 2000->2016 cols (63 chunks of 32);
// pad cols give acc=0 -> exact constant correction 256*bitcast((uint)FEC) in merge.
// Keeps R15's up8 + setprio (R16 A/B: dropping setprio cost ~10%).

typedef __attribute__((ext_vector_type(4))) float f32x4;
typedef __attribute__((ext_vector_type(16))) float f32x16;
typedef __attribute__((ext_vector_type(4))) int i32x4;
typedef __attribute__((ext_vector_type(8))) int i32x8;

constexpr int N = 8192, D = 512, C = 32000;
constexpr int BM = 128;            // rows per block (4 waves x 32 rows)
constexpr int NSPLIT = 16;         // column splits of C
constexpr int CPS = C / NSPLIT;    // 2000 real cols per split
constexpr int GCH = 63;            // padded chunks of 32 cols (2016) per split
constexpr int KS8 = 8;             // 8 k-steps of K=64
constexpr float SCL = 16.0f;
constexpr float LOG2E = 1.4426950408889634f;
constexpr float S2 = SCL * LOG2E;              // folded into A pre-quant
constexpr float COSM = 0.98006657784124163f;  // cos(0.2)
constexpr float SINM = 0.19866933079506122f;  // sin(0.2)
constexpr float EPSC = 1e-7f;
constexpr float EM16 = 1.12535174719259114e-07f;  // exp(-16)
constexpr float FEC = 1064871712.0f;  // Schraudolph zero-mean magic (validated R12)

// fp4 e2m1 magnitude grid {0,.5,1,1.5,2,3,4,6} at codes 0..7.
__device__ __forceinline__ unsigned enc_fp4(float v, float inv) {
  unsigned s = (__float_as_uint(v) >> 31) << 3;
  float m = fabsf(v) * inv;
  float r = m < 2.0f ? 2.0f * m : (m < 4.0f ? m + 2.0f : fmaf(m, 0.5f, 4.0f));
  unsigned q = (unsigned)(r + 0.5f);
  return s | (q > 7u ? 7u : q);
}

// Per-32-block E8M0 scale from block absmax: smallest 2^e with absmax/2^e <= 6.
__device__ __forceinline__ void block_scale(float amax, unsigned& eB, float& inv) {
  unsigned u = __float_as_uint(amax * (1.0f / 6.0f));
  eB = (u >> 23) & 255u;
  if (u & 0x7fffffu) eB += 1u;      // ceil
  if (eB < 1u) eB = 1u;
  if (eB > 254u) eB = 254u;
  inv = __uint_as_float((254u - eB) << 23);  // 2^(127-eB)
}

__device__ __forceinline__ i32x8 up8(i32x4 v) {
  return __builtin_shufflevector(v, v, 0, 1, 2, 3, -1, -1, -1, -1);  // upper undef
}

// x: one wave per row. v = x_hat * S2; per-32-block scale; emit fp4 nibbles
// (row stride 256B) + scale bytes [row][h][ks] (16B/row, h=kb&1, ks=kb>>1).
__global__ void k_norm_x(const float* __restrict__ in, unsigned* __restrict__ xn4,
                         unsigned char* __restrict__ xsc, float* __restrict__ outz) {
  if (blockIdx.x == 0 && threadIdx.x == 0) *outz = 0.0f;
  int w = (blockIdx.x << 2) + (threadIdx.x >> 6);
  int L = threadIdx.x & 63;
  const float* row = in + (size_t)w * D;
  float f[8];
  *(f32x4*)&f[0] = *(const f32x4*)(row + L * 8);
  *(f32x4*)&f[4] = *(const f32x4*)(row + L * 8 + 4);
  float ss = 0.f;
  #pragma unroll
  for (int i = 0; i < 8; ++i) ss += f[i] * f[i];
  #pragma unroll
  for (int m = 1; m <= 32; m <<= 1) ss += __shfl_xor(ss, m, 64);
  float sc = S2 / fmaxf(sqrtf(ss), 1e-12f);
  float v[8], am = 0.f;
  #pragma unroll
  for (int i = 0; i < 8; ++i) { v[i] = f[i] * sc; am = fmaxf(am, fabsf(v[i])); }
  am = fmaxf(am, __shfl_xor(am, 1, 64));
  am = fmaxf(am, __shfl_xor(am, 2, 64));   // quad (= one 32-elem block) absmax
  unsigned eB; float inv;
  block_scale(am, eB, inv);
  unsigned pk = 0;
  #pragma unroll
  for (int j = 0; j < 8; ++j) pk |= enc_fp4(v[j], inv) << (4 * j);
  xn4[(size_t)w * 64 + L] = pk;
  if ((L & 3) == 0) {
    int kb = L >> 2;  // k-block 0..15; kb = 2*ks + h
    xsc[(size_t)w * 16 + (kb & 1) * 8 + (kb >> 1)] = (unsigned char)eB;
  }
}

// w: one block per padded 32-col chunk (grid 16*63). Quantize to fp4 with
// per-32-block scales. Chunk image 8KB: 16B unit at ks*1024 + (h*32+col)*16
// holds col's k in [ks*64+h*32,+32) (lane-contiguous: lane offset = lane*16).
// Scale image 512B: byte [col][h][ks] at col*16 + h*8 + ks. Pad cols -> zeros.
__global__ void k_normw_t(const float* __restrict__ in, unsigned char* __restrict__ wt4,
                          unsigned char* __restrict__ wsc) {
  __shared__ unsigned lbuf[2048];         // 8KB chunk image
  __shared__ unsigned char sbuf[512];     // scale image
  const int tid = threadIdx.x, wv = tid >> 6, L = tid & 63;
  const int gidx = blockIdx.x;
  const int sp = gidx / GCH, within = gidx % GCH;
  #pragma unroll
  for (int t = 0; t < 8; ++t) {
    int rl = t * 4 + wv;  // 0..31 (col within chunk)
    int colin = within * 32 + rl;
    bool valid = colin < CPS;             // wave-uniform
    unsigned pk = 0;
    unsigned eB = 1u;
    if (valid) {
      const float* row = in + ((size_t)sp * CPS + colin) * D;
      float f[8];
      *(f32x4*)&f[0] = *(const f32x4*)(row + L * 8);
      *(f32x4*)&f[4] = *(const f32x4*)(row + L * 8 + 4);
      float ss = 0.f;
      #pragma unroll
      for (int i = 0; i < 8; ++i) ss += f[i] * f[i];
      #pragma unroll
      for (int m = 1; m <= 32; m <<= 1) ss += __shfl_xor(ss, m, 64);
      float sc = 1.0f / fmaxf(sqrtf(ss), 1e-12f);
      float v[8], am = 0.f;
      #pragma unroll
      for (int i = 0; i < 8; ++i) { v[i] = f[i] * sc; am = fmaxf(am, fabsf(v[i])); }
      am = fmaxf(am, __shfl_xor(am, 1, 64));
      am = fmaxf(am, __shfl_xor(am, 2, 64));
      float inv;
      block_scale(am, eB, inv);
      #pragma unroll
      for (int j = 0; j < 8; ++j) pk |= enc_fp4(v[j], inv) << (4 * j);
    }
    // lane L covers k=8L..8L+8: ks=L>>3, h=(L>>2)&1, dword slot (L&3)
    lbuf[(L >> 3) * 256 + (((L >> 2) & 1) * 32 + rl) * 4 + (L & 3)] = pk;
    if ((L & 3) == 0) {
      int kb = L >> 2;
      sbuf[rl * 16 + (kb & 1) * 8 + (kb >> 1)] = (unsigned char)eB;
    }
  }
  __syncthreads();
  uint4* dst = (uint4*)(wt4 + (size_t)gidx * 8192);
  #pragma unroll
  for (int i = 0; i < 2; ++i) dst[i * 256 + tid] = ((const uint4*)lbuf)[i * 256 + tid];
  if (tid < 128)
    ((unsigned*)(wsc + (size_t)gidx * 512))[tid] = ((const unsigned*)sbuf)[tid];
}

// Label-column cosine in f32 (one wave per row) -> coslab[N].
__global__ void k_lab(const float* __restrict__ x, const float* __restrict__ w,
                      const int* __restrict__ labels, float* __restrict__ coslab) {
  int r = (blockIdx.x << 2) + (threadIdx.x >> 6);
  int lane = threadIdx.x & 63;
  const float* xr = x + (size_t)r * D;
  const float* wr = w + (size_t)labels[r] * D;
  f32x4 a = *(const f32x4*)(xr + lane * 8);
  f32x4 b = *(const f32x4*)(xr + lane * 8 + 4);
  f32x4 p = *(const f32x4*)(wr + lane * 8);
  f32x4 q = *(const f32x4*)(wr + lane * 8 + 4);
  float xx = a.x*a.x + a.y*a.y + a.z*a.z + a.w*a.w + b.x*b.x + b.y*b.y + b.z*b.z + b.w*b.w;
  float ww = p.x*p.x + p.y*p.y + p.z*p.z + p.w*p.w + q.x*q.x + q.y*q.y + q.z*q.z + q.w*q.w;
  float xw = a.x*p.x + a.y*p.y + a.z*p.z + a.w*p.w + b.x*q.x + b.y*q.y + b.z*q.z + b.w*q.w;
  #pragma unroll
  for (int m = 1; m <= 32; m <<= 1) {
    xx += __shfl_xor(xx, m, 64);
    ww += __shfl_xor(ww, m, 64);
    xw += __shfl_xor(xw, m, 64);
  }
  if (lane == 0)
    coslab[r] = xw / (fmaxf(sqrtf(xx), 1e-12f) * fmaxf(sqrtf(ww), 1e-12f));
}

// One k-step with LITERAL ks 0..7 (opsel immediates: word KSL>>2, byte KSL&3).
// SEED seeds the 16-wide acc from fzero. DOEXP interleaves 4 fast-exp2 of the
// previous chunk's acc at EBASE. Staggered b refill from chunk CHNEXT.
#define KS_STEP(KSL, ACC, SEED, DOEXP, EBASE, PACC, CHNEXT)                   \
    __builtin_amdgcn_s_setprio(1);                                            \
    ACC = __builtin_amdgcn_mfma_scale_f32_32x32x64_f8f6f4(                    \
        up8(af4[KSL]), up8(b4[KSL]), (SEED) ? fzero : ACC,                    \
        4, 4, (KSL) & 3, ((KSL) >> 2) ? ascB : ascA,                          \
              (KSL) & 3, ((KSL) >> 2) ? bscB : bscA);                         \
    __builtin_amdgcn_s_setprio(0);                                            \
    if (DOEXP) {                                                              \
      _Pragma("unroll")                                                       \
      for (int r = 0; r < 4; ++r)                                             \
        accS[(EBASE) + r] += __uint_as_float(                                 \
            (unsigned)fmaf(PACC[(EBASE) + r], 8388608.0f, FEC));              \
    }                                                                         \
    b4[KSL] = *(const i32x4*)(gb + (size_t)(CHNEXT) * 8192 + (KSL) * 1024);

#define CHUNK_STEP(ACC, PACC, DOEXP, CHNEXT)                                  \
  {                                                                           \
    int nscA = *(const int*)(gsc + (size_t)(CHNEXT) * 512);                   \
    int nscB = *(const int*)(gsc + (size_t)(CHNEXT) * 512 + 4);               \
    KS_STEP(0, ACC, true,  false, 0,  PACC, CHNEXT)                           \
    KS_STEP(1, ACC, false, DOEXP, 0,  PACC, CHNEXT)                           \
    KS_STEP(2, ACC, false, false, 0,  PACC, CHNEXT)                           \
    KS_STEP(3, ACC, false, DOEXP, 4,  PACC, CHNEXT)                           \
    KS_STEP(4, ACC, false, false, 0,  PACC, CHNEXT)                           \
    KS_STEP(5, ACC, false, DOEXP, 8,  PACC, CHNEXT)                           \
    KS_STEP(6, ACC, false, false, 0,  PACC, CHNEXT)                           \
    KS_STEP(7, ACC, false, DOEXP, 12, PACC, CHNEXT)                           \
    bscA = nscA; bscB = nscB;                                                 \
  }

// Fused MX-fp4 32x32x64 GEMM, barrier-free, 4 waves/SIMD, acc ping-pong.
__global__ __launch_bounds__(256, 4) void k_fused(
    const unsigned char* __restrict__ xn4, const unsigned char* __restrict__ xsc,
    const unsigned char* __restrict__ wt4, const unsigned char* __restrict__ wsc,
    float* __restrict__ pS) {
  const int tid = threadIdx.x;
  const int wv = tid >> 6, lane = tid & 63;
  const int h = lane >> 5, c = lane & 31;
  const int bid = blockIdx.x;
  const int logical = (bid & 7) * 128 + (bid >> 3);  // 1024 = 8*128 XCD swizzle
  const int sp = logical >> 6;          // 0..15 (2 splits per XCD)
  const int rb = logical & 63;          // 0..63
  const int row0 = rb * BM + wv * 32;   // this wave's 32 rows (one 32x32 tile)

  // A-tile fully K-resident: af4[ks] = 16B at row*256 + ks*32 + h*16
  // (k in [ks*64 + h*32, +32)). Scales: words at row*16 + h*8 (+4).
  i32x4 af4[KS8];
  int ascA, ascB;
  {
    const unsigned char* xr = xn4 + (size_t)(row0 + c) * 256 + h * 16;
    #pragma unroll
    for (int ks = 0; ks < KS8; ++ks) af4[ks] = *(const i32x4*)(xr + ks * 32);
    ascA = *(const int*)(xsc + (size_t)(row0 + c) * 16 + h * 8);
    ascB = *(const int*)(xsc + (size_t)(row0 + c) * 16 + h * 8 + 4);
  }

  float accS[16];
  #pragma unroll
  for (int i = 0; i < 16; ++i) accS[i] = 0.0f;

  const f32x16 fzero = (f32x16)0.0f;

  const unsigned char* gb = wt4 + (size_t)(sp * GCH) * 8192 + lane * 16;
  const unsigned char* gsc = wsc + (size_t)(sp * GCH) * 512 + c * 16 + h * 8;

  i32x4 b4[KS8];
  #pragma unroll
  for (int ks = 0; ks < KS8; ++ks) b4[ks] = *(const i32x4*)(gb + ks * 1024);
  int bscA = *(const int*)gsc;
  int bscB = *(const int*)(gsc + 4);

  f32x16 accP, accQ;

  // Prologue: chunk 0 -> accP (no exps); prefetch chunk 1.
  CHUNK_STEP(accP, accQ, false, 1)

  for (int ch = 1; ch + 1 < GCH; ch += 2) {
    CHUNK_STEP(accQ, accP, true, ch + 1)
    CHUNK_STEP(accP, accQ, true, (ch + 2 < GCH ? ch + 2 : GCH - 1))
  }
  // Tail: exps of accP (chunk 62).
  #pragma unroll
  for (int i = 0; i < 16; ++i)
    accS[i] += __uint_as_float((unsigned)fmaf(accP[i], 8388608.0f, FEC));

  // Sum over the 32 col-lanes (within each half); write per-(row,split) partials.
  #pragma unroll
  for (int i = 0; i < 16; ++i) {
    float S = accS[i];
    #pragma unroll
    for (int m = 1; m <= 16; m <<= 1) S += __shfl_xor(S, m, 64);
    accS[i] = S;
  }
  if (c == 0) {
    #pragma unroll
    for (int i = 0; i < 16; ++i) {
      int rl = (i & 3) + 8 * (i >> 2) + 4 * h;  // verified 32x32 C/D row map
      pS[(size_t)sp * N + row0 + rl] = accS[i];
    }
  }
}
#undef CHUNK_STEP
#undef KS_STEP

// Merge: S over splits; subtract exact pad contribution (256 cols x fastexp(0));
// x e^-16; swap plain label term for f32 margin term; NLL mean.
__global__ void k_merge(const float* __restrict__ pS, const float* __restrict__ coslab,
                        float* __restrict__ out) {
  int row = blockIdx.x * 256 + threadIdx.x;
  float S = 0.0f;
  #pragma unroll
  for (int s = 0; s < NSPLIT; ++s) S += pS[(size_t)s * N + row];
  S -= 256.0f * __uint_as_float((unsigned)FEC);  // exact pad-col correction
  float cl = coslab[row];
  float zp = SCL * cl;
  float ccl = fminf(fmaxf(cl, -1.0f + EPSC), 1.0f - EPSC);
  float zm = SCL * (ccl * COSM - sqrtf(1.0f - ccl * ccl) * SINM);
  float denom = S * EM16 - __expf(zp - SCL) + __expf(zm - SCL);
  float nll = SCL + logf(denom) - zm;
  #pragma unroll
  for (int m = 1; m <= 32; m <<= 1) nll += __shfl_xor(nll, m, 64);
  __shared__ float part[4];
  if ((threadIdx.x & 63) == 0) part[threadIdx.x >> 6] = nll;
  __syncthreads();
  if (threadIdx.x == 0)
    atomicAdd(out, (part[0] + part[1] + part[2] + part[3]) * (1.0f / N));
}

extern "C" void kernel_launch(void* const* d_in, const int* in_sizes, int n_in,
                              void* d_out, int out_size, void* d_ws, size_t ws_size,
                              hipStream_t stream) {
  const float* x = (const float*)d_in[0];
  const float* w = (const float*)d_in[1];
  const int* labels = (const int*)d_in[2];
  float* out = (float*)d_out;

  // ws: xn4 [N*256B] | xsc [N*16B] | wt4 [16*63*8KB] | wsc [16*63*512B]
  //   | pS f32 [NSPLIT*N] | coslab f32 [N]
  unsigned char* xn4 = (unsigned char*)d_ws;
  unsigned char* xsc = xn4 + (size_t)N * 256;
  unsigned char* wt4 = xsc + (size_t)N * 16;
  unsigned char* wsc = wt4 + (size_t)NSPLIT * GCH * 8192;
  float* pS = (float*)(wsc + (size_t)NSPLIT * GCH * 512);
  float* coslab = pS + (size_t)NSPLIT * N;

  hipLaunchKernelGGL(k_norm_x, dim3(N / 4), dim3(256), 0, stream,
                     x, (unsigned*)xn4, xsc, out);
  hipLaunchKernelGGL(k_normw_t, dim3(NSPLIT * GCH), dim3(256), 0, stream, w, wt4, wsc);
  hipLaunchKernelGGL(k_lab, dim3(N / 4), dim3(256), 0, stream, x, w, labels, coslab);
  hipLaunchKernelGGL(k_fused, dim3(64 * NSPLIT), dim3(256), 0, stream,
                     xn4, xsc, wt4, wsc, pS);
  hipLaunchKernelGGL(k_merge, dim3(N / 256), dim3(256), 0, stream, pS, coslab, out);
}

// Round 20
// 117.454 us; speedup vs baseline: 3.4275x; 3.4275x over previous
//
#include <hip/hip_runtime.h>

// ArcMarginLoss fused: normalize -> MX-fp4 MFMA GEMM + fixed-max softmax -> NLL mean.
// N=8192, D=512, C=32000, scale=16, margin=0.2.
// R20: R19's 32x32x64 fp4 shape, register-budget-fixed. R19 spilled (WRITE 1.1GB):
// ping-pong's 2x f32x16 acc pushed past the 128-reg cap at 4 waves/SIMD. Fix:
// single acc, exp epilogue after the chunk's 8 MFMAs (dependency covered by 4
// waves/SIMD TLP instead of acc ping-pong). af4 32 + b4 32 + acc 16 + accS 16
// + misc ~= 116 <= 128. All layouts/quantizers from R19 (absmax-verified).

typedef __attribute__((ext_vector_type(4))) float f32x4;
typedef __attribute__((ext_vector_type(16))) float f32x16;
typedef __attribute__((ext_vector_type(4))) int i32x4;
typedef __attribute__((ext_vector_type(8))) int i32x8;

constexpr int N = 8192, D = 512, C = 32000;
constexpr int BM = 128;            // rows per block (4 waves x 32 rows)
constexpr int NSPLIT = 16;         // column splits of C
constexpr int CPS = C / NSPLIT;    // 2000 real cols per split
constexpr int GCH = 63;            // padded chunks of 32 cols (2016) per split
constexpr int KS8 = 8;             // 8 k-steps of K=64
constexpr float SCL = 16.0f;
constexpr float LOG2E = 1.4426950408889634f;
constexpr float S2 = SCL * LOG2E;              // folded into A pre-quant
constexpr float COSM = 0.98006657784124163f;  // cos(0.2)
constexpr float SINM = 0.19866933079506122f;  // sin(0.2)
constexpr float EPSC = 1e-7f;
constexpr float EM16 = 1.12535174719259114e-07f;  // exp(-16)
constexpr float FEC = 1064871712.0f;  // Schraudolph zero-mean magic (validated R12)

// fp4 e2m1 magnitude grid {0,.5,1,1.5,2,3,4,6} at codes 0..7.
__device__ __forceinline__ unsigned enc_fp4(float v, float inv) {
  unsigned s = (__float_as_uint(v) >> 31) << 3;
  float m = fabsf(v) * inv;
  float r = m < 2.0f ? 2.0f * m : (m < 4.0f ? m + 2.0f : fmaf(m, 0.5f, 4.0f));
  unsigned q = (unsigned)(r + 0.5f);
  return s | (q > 7u ? 7u : q);
}

// Per-32-block E8M0 scale from block absmax: smallest 2^e with absmax/2^e <= 6.
__device__ __forceinline__ void block_scale(float amax, unsigned& eB, float& inv) {
  unsigned u = __float_as_uint(amax * (1.0f / 6.0f));
  eB = (u >> 23) & 255u;
  if (u & 0x7fffffu) eB += 1u;      // ceil
  if (eB < 1u) eB = 1u;
  if (eB > 254u) eB = 254u;
  inv = __uint_as_float((254u - eB) << 23);  // 2^(127-eB)
}

__device__ __forceinline__ i32x8 up8(i32x4 v) {
  return __builtin_shufflevector(v, v, 0, 1, 2, 3, -1, -1, -1, -1);  // upper undef
}

// x: one wave per row. v = x_hat * S2; per-32-block scale; emit fp4 nibbles
// (row stride 256B) + scale bytes [row][h][ks] (16B/row, h=kb&1, ks=kb>>1).
__global__ void k_norm_x(const float* __restrict__ in, unsigned* __restrict__ xn4,
                         unsigned char* __restrict__ xsc, float* __restrict__ outz) {
  if (blockIdx.x == 0 && threadIdx.x == 0) *outz = 0.0f;
  int w = (blockIdx.x << 2) + (threadIdx.x >> 6);
  int L = threadIdx.x & 63;
  const float* row = in + (size_t)w * D;
  float f[8];
  *(f32x4*)&f[0] = *(const f32x4*)(row + L * 8);
  *(f32x4*)&f[4] = *(const f32x4*)(row + L * 8 + 4);
  float ss = 0.f;
  #pragma unroll
  for (int i = 0; i < 8; ++i) ss += f[i] * f[i];
  #pragma unroll
  for (int m = 1; m <= 32; m <<= 1) ss += __shfl_xor(ss, m, 64);
  float sc = S2 / fmaxf(sqrtf(ss), 1e-12f);
  float v[8], am = 0.f;
  #pragma unroll
  for (int i = 0; i < 8; ++i) { v[i] = f[i] * sc; am = fmaxf(am, fabsf(v[i])); }
  am = fmaxf(am, __shfl_xor(am, 1, 64));
  am = fmaxf(am, __shfl_xor(am, 2, 64));   // quad (= one 32-elem block) absmax
  unsigned eB; float inv;
  block_scale(am, eB, inv);
  unsigned pk = 0;
  #pragma unroll
  for (int j = 0; j < 8; ++j) pk |= enc_fp4(v[j], inv) << (4 * j);
  xn4[(size_t)w * 64 + L] = pk;
  if ((L & 3) == 0) {
    int kb = L >> 2;  // k-block 0..15; kb = 2*ks + h
    xsc[(size_t)w * 16 + (kb & 1) * 8 + (kb >> 1)] = (unsigned char)eB;
  }
}

// w: one block per padded 32-col chunk (grid 16*63). Quantize to fp4 with
// per-32-block scales. Chunk image 8KB: 16B unit at ks*1024 + (h*32+col)*16
// holds col's k in [ks*64+h*32,+32) (lane-contiguous: lane offset = lane*16).
// Scale image 512B: byte [col][h][ks] at col*16 + h*8 + ks. Pad cols -> zeros.
__global__ void k_normw_t(const float* __restrict__ in, unsigned char* __restrict__ wt4,
                          unsigned char* __restrict__ wsc) {
  __shared__ unsigned lbuf[2048];         // 8KB chunk image
  __shared__ unsigned char sbuf[512];     // scale image
  const int tid = threadIdx.x, wv = tid >> 6, L = tid & 63;
  const int gidx = blockIdx.x;
  const int sp = gidx / GCH, within = gidx % GCH;
  #pragma unroll
  for (int t = 0; t < 8; ++t) {
    int rl = t * 4 + wv;  // 0..31 (col within chunk)
    int colin = within * 32 + rl;
    bool valid = colin < CPS;             // wave-uniform
    unsigned pk = 0;
    unsigned eB = 1u;
    if (valid) {
      const float* row = in + ((size_t)sp * CPS + colin) * D;
      float f[8];
      *(f32x4*)&f[0] = *(const f32x4*)(row + L * 8);
      *(f32x4*)&f[4] = *(const f32x4*)(row + L * 8 + 4);
      float ss = 0.f;
      #pragma unroll
      for (int i = 0; i < 8; ++i) ss += f[i] * f[i];
      #pragma unroll
      for (int m = 1; m <= 32; m <<= 1) ss += __shfl_xor(ss, m, 64);
      float sc = 1.0f / fmaxf(sqrtf(ss), 1e-12f);
      float v[8], am = 0.f;
      #pragma unroll
      for (int i = 0; i < 8; ++i) { v[i] = f[i] * sc; am = fmaxf(am, fabsf(v[i])); }
      am = fmaxf(am, __shfl_xor(am, 1, 64));
      am = fmaxf(am, __shfl_xor(am, 2, 64));
      float inv;
      block_scale(am, eB, inv);
      #pragma unroll
      for (int j = 0; j < 8; ++j) pk |= enc_fp4(v[j], inv) << (4 * j);
    }
    // lane L covers k=8L..8L+8: ks=L>>3, h=(L>>2)&1, dword slot (L&3)
    lbuf[(L >> 3) * 256 + (((L >> 2) & 1) * 32 + rl) * 4 + (L & 3)] = pk;
    if ((L & 3) == 0) {
      int kb = L >> 2;
      sbuf[rl * 16 + (kb & 1) * 8 + (kb >> 1)] = (unsigned char)eB;
    }
  }
  __syncthreads();
  uint4* dst = (uint4*)(wt4 + (size_t)gidx * 8192);
  #pragma unroll
  for (int i = 0; i < 2; ++i) dst[i * 256 + tid] = ((const uint4*)lbuf)[i * 256 + tid];
  if (tid < 128)
    ((unsigned*)(wsc + (size_t)gidx * 512))[tid] = ((const unsigned*)sbuf)[tid];
}

// Label-column cosine in f32 (one wave per row) -> coslab[N].
__global__ void k_lab(const float* __restrict__ x, const float* __restrict__ w,
                      const int* __restrict__ labels, float* __restrict__ coslab) {
  int r = (blockIdx.x << 2) + (threadIdx.x >> 6);
  int lane = threadIdx.x & 63;
  const float* xr = x + (size_t)r * D;
  const float* wr = w + (size_t)labels[r] * D;
  f32x4 a = *(const f32x4*)(xr + lane * 8);
  f32x4 b = *(const f32x4*)(xr + lane * 8 + 4);
  f32x4 p = *(const f32x4*)(wr + lane * 8);
  f32x4 q = *(const f32x4*)(wr + lane * 8 + 4);
  float xx = a.x*a.x + a.y*a.y + a.z*a.z + a.w*a.w + b.x*b.x + b.y*b.y + b.z*b.z + b.w*b.w;
  float ww = p.x*p.x + p.y*p.y + p.z*p.z + p.w*p.w + q.x*q.x + q.y*q.y + q.z*q.z + q.w*q.w;
  float xw = a.x*p.x + a.y*p.y + a.z*p.z + a.w*p.w + b.x*q.x + b.y*q.y + b.z*q.z + b.w*q.w;
  #pragma unroll
  for (int m = 1; m <= 32; m <<= 1) {
    xx += __shfl_xor(xx, m, 64);
    ww += __shfl_xor(ww, m, 64);
    xw += __shfl_xor(xw, m, 64);
  }
  if (lane == 0)
    coslab[r] = xw / (fmaxf(sqrtf(xx), 1e-12f) * fmaxf(sqrtf(ww), 1e-12f));
}

// One k-step with LITERAL ks 0..7 (opsel immediates: word KSL>>2, byte KSL&3).
// ks=0 seeds acc from fzero. Staggered b refill from chunk CHNEXT.
#define KS_STEP(KSL, CHNEXT)                                                  \
    __builtin_amdgcn_s_setprio(1);                                            \
    acc = __builtin_amdgcn_mfma_scale_f32_32x32x64_f8f6f4(                    \
        up8(af4[KSL]), up8(b4[KSL]), (KSL) == 0 ? fzero : acc,                \
        4, 4, (KSL) & 3, ((KSL) >> 2) ? ascB : ascA,                          \
              (KSL) & 3, ((KSL) >> 2) ? bscB : bscA);                         \
    __builtin_amdgcn_s_setprio(0);                                            \
    b4[KSL] = *(const i32x4*)(gb + (size_t)(CHNEXT) * 8192 + (KSL) * 1024);

// One chunk: 8 MFMAs into acc, then 16 fast-exp2 into accS (TLP covers the
// MFMA->exp dependency at 4 waves/SIMD). Scale words refilled alongside.
#define CHUNK_STEP(CHNEXT)                                                    \
  {                                                                           \
    int nscA = *(const int*)(gsc + (size_t)(CHNEXT) * 512);                   \
    int nscB = *(const int*)(gsc + (size_t)(CHNEXT) * 512 + 4);               \
    KS_STEP(0, CHNEXT)                                                        \
    KS_STEP(1, CHNEXT)                                                        \
    KS_STEP(2, CHNEXT)                                                        \
    KS_STEP(3, CHNEXT)                                                        \
    KS_STEP(4, CHNEXT)                                                        \
    KS_STEP(5, CHNEXT)                                                        \
    KS_STEP(6, CHNEXT)                                                        \
    KS_STEP(7, CHNEXT)                                                        \
    _Pragma("unroll")                                                         \
    for (int i = 0; i < 16; ++i)                                              \
      accS[i] += __uint_as_float((unsigned)fmaf(acc[i], 8388608.0f, FEC));    \
    bscA = nscA; bscB = nscB;                                                 \
  }

// Fused MX-fp4 32x32x64 GEMM, barrier-free, 4 waves/SIMD, single acc.
__global__ __launch_bounds__(256, 4) void k_fused(
    const unsigned char* __restrict__ xn4, const unsigned char* __restrict__ xsc,
    const unsigned char* __restrict__ wt4, const unsigned char* __restrict__ wsc,
    float* __restrict__ pS) {
  const int tid = threadIdx.x;
  const int wv = tid >> 6, lane = tid & 63;
  const int h = lane >> 5, c = lane & 31;
  const int bid = blockIdx.x;
  const int logical = (bid & 7) * 128 + (bid >> 3);  // 1024 = 8*128 XCD swizzle
  const int sp = logical >> 6;          // 0..15 (2 splits per XCD)
  const int rb = logical & 63;          // 0..63
  const int row0 = rb * BM + wv * 32;   // this wave's 32 rows (one 32x32 tile)

  // A-tile fully K-resident: af4[ks] = 16B at row*256 + ks*32 + h*16
  // (k in [ks*64 + h*32, +32)). Scales: words at row*16 + h*8 (+4).
  i32x4 af4[KS8];
  int ascA, ascB;
  {
    const unsigned char* xr = xn4 + (size_t)(row0 + c) * 256 + h * 16;
    #pragma unroll
    for (int ks = 0; ks < KS8; ++ks) af4[ks] = *(const i32x4*)(xr + ks * 32);
    ascA = *(const int*)(xsc + (size_t)(row0 + c) * 16 + h * 8);
    ascB = *(const int*)(xsc + (size_t)(row0 + c) * 16 + h * 8 + 4);
  }

  float accS[16];
  #pragma unroll
  for (int i = 0; i < 16; ++i) accS[i] = 0.0f;

  const f32x16 fzero = (f32x16)0.0f;

  const unsigned char* gb = wt4 + (size_t)(sp * GCH) * 8192 + lane * 16;
  const unsigned char* gsc = wsc + (size_t)(sp * GCH) * 512 + c * 16 + h * 8;

  i32x4 b4[KS8];
  #pragma unroll
  for (int ks = 0; ks < KS8; ++ks) b4[ks] = *(const i32x4*)(gb + ks * 1024);
  int bscA = *(const int*)gsc;
  int bscB = *(const int*)(gsc + 4);

  f32x16 acc;

  for (int ch = 0; ch < GCH; ++ch) {
    int cn = ch + 1 < GCH ? ch + 1 : GCH - 1;
    CHUNK_STEP(cn)
  }

  // Sum over the 32 col-lanes (within each half); write per-(row,split) partials.
  #pragma unroll
  for (int i = 0; i < 16; ++i) {
    float S = accS[i];
    #pragma unroll
    for (int m = 1; m <= 16; m <<= 1) S += __shfl_xor(S, m, 64);
    accS[i] = S;
  }
  if (c == 0) {
    #pragma unroll
    for (int i = 0; i < 16; ++i) {
      int rl = (i & 3) + 8 * (i >> 2) + 4 * h;  // verified 32x32 C/D row map
      pS[(size_t)sp * N + row0 + rl] = accS[i];
    }
  }
}
#undef CHUNK_STEP
#undef KS_STEP

// Merge: S over splits; subtract exact pad contribution (256 cols x fastexp(0));
// x e^-16; swap plain label term for f32 margin term; NLL mean.
__global__ void k_merge(const float* __restrict__ pS, const float* __restrict__ coslab,
                        float* __restrict__ out) {
  int row = blockIdx.x * 256 + threadIdx.x;
  float S = 0.0f;
  #pragma unroll
  for (int s = 0; s < NSPLIT; ++s) S += pS[(size_t)s * N + row];
  S -= 256.0f * __uint_as_float((unsigned)FEC);  // exact pad-col correction
  float cl = coslab[row];
  float zp = SCL * cl;
  float ccl = fminf(fmaxf(cl, -1.0f + EPSC), 1.0f - EPSC);
  float zm = SCL * (ccl * COSM - sqrtf(1.0f - ccl * ccl) * SINM);
  float denom = S * EM16 - __expf(zp - SCL) + __expf(zm - SCL);
  float nll = SCL + logf(denom) - zm;
  #pragma unroll
  for (int m = 1; m <= 32; m <<= 1) nll += __shfl_xor(nll, m, 64);
  __shared__ float part[4];
  if ((threadIdx.x & 63) == 0) part[threadIdx.x >> 6] = nll;
  __syncthreads();
  if (threadIdx.x == 0)
    atomicAdd(out, (part[0] + part[1] + part[2] + part[3]) * (1.0f / N));
}

extern "C" void kernel_launch(void* const* d_in, const int* in_sizes, int n_in,
                              void* d_out, int out_size, void* d_ws, size_t ws_size,
                              hipStream_t stream) {
  const float* x = (const float*)d_in[0];
  const float* w = (const float*)d_in[1];
  const int* labels = (const int*)d_in[2];
  float* out = (float*)d_out;

  // ws: xn4 [N*256B] | xsc [N*16B] | wt4 [16*63*8KB] | wsc [16*63*512B]
  //   | pS f32 [NSPLIT*N] | coslab f32 [N]
  unsigned char* xn4 = (unsigned char*)d_ws;
  unsigned char* xsc = xn4 + (size_t)N * 256;
  unsigned char* wt4 = xsc + (size_t)N * 16;
  unsigned char* wsc = wt4 + (size_t)NSPLIT * GCH * 8192;
  float* pS = (float*)(wsc + (size_t)NSPLIT * GCH * 512);
  float* coslab = pS + (size_t)NSPLIT * N;

  hipLaunchKernelGGL(k_norm_x, dim3(N / 4), dim3(256), 0, stream,
                     x, (unsigned*)xn4, xsc, out);
  hipLaunchKernelGGL(k_normw_t, dim3(NSPLIT * GCH), dim3(256), 0, stream, w, wt4, wsc);
  hipLaunchKernelGGL(k_lab, dim3(N / 4), dim3(256), 0, stream, x, w, labels, coslab);
  hipLaunchKernelGGL(k_fused, dim3(64 * NSPLIT), dim3(256), 0, stream,
                     xn4, xsc, wt4, wsc, pS);
  hipLaunchKernelGGL(k_merge, dim3(N / 256), dim3(256), 0, stream, pS, coslab, out);
}

// Round 21
// 103.764 us; speedup vs baseline: 3.8797x; 1.1319x over previous
//
#include <hip/hip_runtime.h>

// ArcMarginLoss fused: normalize -> MX-fp4 MFMA GEMM + fixed-max softmax -> NLL mean.
// N=8192, D=512, C=32000, scale=16, margin=0.2.
// R21: L2-bandwidth hypothesis test. All rounds streamed ~2.06GB of B through L2
// (every wave reads its split's full slice) -> ~60us L2 floor = the 10-round
// "unattributed gap". Fix: 2 A-tiles per wave (64 rows), each B-fragment feeds
// 2 MFMAs -> waves halve -> 1.03GB L2 (~30us). Per-SIMD issue totals unchanged,
// so any improvement isolates L2 relief. ~190 VGPR at launch_bounds(256,2),
// grid 512 = 2 blocks/CU. 32x32x64 shape + all R20-verified layouts kept.

typedef __attribute__((ext_vector_type(4))) float f32x4;
typedef __attribute__((ext_vector_type(16))) float f32x16;
typedef __attribute__((ext_vector_type(4))) int i32x4;
typedef __attribute__((ext_vector_type(8))) int i32x8;

constexpr int N = 8192, D = 512, C = 32000;
constexpr int BM = 256;            // rows per block (4 waves x 2 tiles x 32 rows)
constexpr int NSPLIT = 16;         // column splits of C
constexpr int CPS = C / NSPLIT;    // 2000 real cols per split
constexpr int GCH = 63;            // padded chunks of 32 cols (2016) per split
constexpr int KS8 = 8;             // 8 k-steps of K=64
constexpr float SCL = 16.0f;
constexpr float LOG2E = 1.4426950408889634f;
constexpr float S2 = SCL * LOG2E;              // folded into A pre-quant
constexpr float COSM = 0.98006657784124163f;  // cos(0.2)
constexpr float SINM = 0.19866933079506122f;  // sin(0.2)
constexpr float EPSC = 1e-7f;
constexpr float EM16 = 1.12535174719259114e-07f;  // exp(-16)
constexpr float FEC = 1064871712.0f;  // Schraudolph zero-mean magic (validated R12)

// fp4 e2m1 magnitude grid {0,.5,1,1.5,2,3,4,6} at codes 0..7.
__device__ __forceinline__ unsigned enc_fp4(float v, float inv) {
  unsigned s = (__float_as_uint(v) >> 31) << 3;
  float m = fabsf(v) * inv;
  float r = m < 2.0f ? 2.0f * m : (m < 4.0f ? m + 2.0f : fmaf(m, 0.5f, 4.0f));
  unsigned q = (unsigned)(r + 0.5f);
  return s | (q > 7u ? 7u : q);
}

// Per-32-block E8M0 scale from block absmax: smallest 2^e with absmax/2^e <= 6.
__device__ __forceinline__ void block_scale(float amax, unsigned& eB, float& inv) {
  unsigned u = __float_as_uint(amax * (1.0f / 6.0f));
  eB = (u >> 23) & 255u;
  if (u & 0x7fffffu) eB += 1u;      // ceil
  if (eB < 1u) eB = 1u;
  if (eB > 254u) eB = 254u;
  inv = __uint_as_float((254u - eB) << 23);  // 2^(127-eB)
}

__device__ __forceinline__ i32x8 up8(i32x4 v) {
  return __builtin_shufflevector(v, v, 0, 1, 2, 3, -1, -1, -1, -1);  // upper undef
}

// x: one wave per row. v = x_hat * S2; per-32-block scale; emit fp4 nibbles
// (row stride 256B) + scale bytes [row][h][ks] (16B/row, h=kb&1, ks=kb>>1).
__global__ void k_norm_x(const float* __restrict__ in, unsigned* __restrict__ xn4,
                         unsigned char* __restrict__ xsc, float* __restrict__ outz) {
  if (blockIdx.x == 0 && threadIdx.x == 0) *outz = 0.0f;
  int w = (blockIdx.x << 2) + (threadIdx.x >> 6);
  int L = threadIdx.x & 63;
  const float* row = in + (size_t)w * D;
  float f[8];
  *(f32x4*)&f[0] = *(const f32x4*)(row + L * 8);
  *(f32x4*)&f[4] = *(const f32x4*)(row + L * 8 + 4);
  float ss = 0.f;
  #pragma unroll
  for (int i = 0; i < 8; ++i) ss += f[i] * f[i];
  #pragma unroll
  for (int m = 1; m <= 32; m <<= 1) ss += __shfl_xor(ss, m, 64);
  float sc = S2 / fmaxf(sqrtf(ss), 1e-12f);
  float v[8], am = 0.f;
  #pragma unroll
  for (int i = 0; i < 8; ++i) { v[i] = f[i] * sc; am = fmaxf(am, fabsf(v[i])); }
  am = fmaxf(am, __shfl_xor(am, 1, 64));
  am = fmaxf(am, __shfl_xor(am, 2, 64));   // quad (= one 32-elem block) absmax
  unsigned eB; float inv;
  block_scale(am, eB, inv);
  unsigned pk = 0;
  #pragma unroll
  for (int j = 0; j < 8; ++j) pk |= enc_fp4(v[j], inv) << (4 * j);
  xn4[(size_t)w * 64 + L] = pk;
  if ((L & 3) == 0) {
    int kb = L >> 2;  // k-block 0..15; kb = 2*ks + h
    xsc[(size_t)w * 16 + (kb & 1) * 8 + (kb >> 1)] = (unsigned char)eB;
  }
}

// w: one block per padded 32-col chunk (grid 16*63). Quantize to fp4 with
// per-32-block scales. Chunk image 8KB: 16B unit at ks*1024 + (h*32+col)*16
// holds col's k in [ks*64+h*32,+32) (lane-contiguous: lane offset = lane*16).
// Scale image 512B: byte [col][h][ks] at col*16 + h*8 + ks. Pad cols -> zeros.
__global__ void k_normw_t(const float* __restrict__ in, unsigned char* __restrict__ wt4,
                          unsigned char* __restrict__ wsc) {
  __shared__ unsigned lbuf[2048];         // 8KB chunk image
  __shared__ unsigned char sbuf[512];     // scale image
  const int tid = threadIdx.x, wv = tid >> 6, L = tid & 63;
  const int gidx = blockIdx.x;
  const int sp = gidx / GCH, within = gidx % GCH;
  #pragma unroll
  for (int t = 0; t < 8; ++t) {
    int rl = t * 4 + wv;  // 0..31 (col within chunk)
    int colin = within * 32 + rl;
    bool valid = colin < CPS;             // wave-uniform
    unsigned pk = 0;
    unsigned eB = 1u;
    if (valid) {
      const float* row = in + ((size_t)sp * CPS + colin) * D;
      float f[8];
      *(f32x4*)&f[0] = *(const f32x4*)(row + L * 8);
      *(f32x4*)&f[4] = *(const f32x4*)(row + L * 8 + 4);
      float ss = 0.f;
      #pragma unroll
      for (int i = 0; i < 8; ++i) ss += f[i] * f[i];
      #pragma unroll
      for (int m = 1; m <= 32; m <<= 1) ss += __shfl_xor(ss, m, 64);
      float sc = 1.0f / fmaxf(sqrtf(ss), 1e-12f);
      float v[8], am = 0.f;
      #pragma unroll
      for (int i = 0; i < 8; ++i) { v[i] = f[i] * sc; am = fmaxf(am, fabsf(v[i])); }
      am = fmaxf(am, __shfl_xor(am, 1, 64));
      am = fmaxf(am, __shfl_xor(am, 2, 64));
      float inv;
      block_scale(am, eB, inv);
      #pragma unroll
      for (int j = 0; j < 8; ++j) pk |= enc_fp4(v[j], inv) << (4 * j);
    }
    // lane L covers k=8L..8L+8: ks=L>>3, h=(L>>2)&1, dword slot (L&3)
    lbuf[(L >> 3) * 256 + (((L >> 2) & 1) * 32 + rl) * 4 + (L & 3)] = pk;
    if ((L & 3) == 0) {
      int kb = L >> 2;
      sbuf[rl * 16 + (kb & 1) * 8 + (kb >> 1)] = (unsigned char)eB;
    }
  }
  __syncthreads();
  uint4* dst = (uint4*)(wt4 + (size_t)gidx * 8192);
  #pragma unroll
  for (int i = 0; i < 2; ++i) dst[i * 256 + tid] = ((const uint4*)lbuf)[i * 256 + tid];
  if (tid < 128)
    ((unsigned*)(wsc + (size_t)gidx * 512))[tid] = ((const unsigned*)sbuf)[tid];
}

// Label-column cosine in f32 (one wave per row) -> coslab[N].
__global__ void k_lab(const float* __restrict__ x, const float* __restrict__ w,
                      const int* __restrict__ labels, float* __restrict__ coslab) {
  int r = (blockIdx.x << 2) + (threadIdx.x >> 6);
  int lane = threadIdx.x & 63;
  const float* xr = x + (size_t)r * D;
  const float* wr = w + (size_t)labels[r] * D;
  f32x4 a = *(const f32x4*)(xr + lane * 8);
  f32x4 b = *(const f32x4*)(xr + lane * 8 + 4);
  f32x4 p = *(const f32x4*)(wr + lane * 8);
  f32x4 q = *(const f32x4*)(wr + lane * 8 + 4);
  float xx = a.x*a.x + a.y*a.y + a.z*a.z + a.w*a.w + b.x*b.x + b.y*b.y + b.z*b.z + b.w*b.w;
  float ww = p.x*p.x + p.y*p.y + p.z*p.z + p.w*p.w + q.x*q.x + q.y*q.y + q.z*q.z + q.w*q.w;
  float xw = a.x*p.x + a.y*p.y + a.z*p.z + a.w*p.w + b.x*q.x + b.y*q.y + b.z*q.z + b.w*q.w;
  #pragma unroll
  for (int m = 1; m <= 32; m <<= 1) {
    xx += __shfl_xor(xx, m, 64);
    ww += __shfl_xor(ww, m, 64);
    xw += __shfl_xor(xw, m, 64);
  }
  if (lane == 0)
    coslab[r] = xw / (fmaxf(sqrtf(xx), 1e-12f) * fmaxf(sqrtf(ww), 1e-12f));
}

// One k-step with LITERAL ks 0..7 (opsel immediates: word KSL>>2, byte KSL&3).
// TWO MFMAs (tile 0, tile 1) share b4[KSL] -> B-reuse 2. ks=0 seeds from fzero.
// Staggered b refill from chunk CHNEXT.
#define KS_STEP(KSL, CHNEXT)                                                  \
    __builtin_amdgcn_s_setprio(1);                                            \
    acc0 = __builtin_amdgcn_mfma_scale_f32_32x32x64_f8f6f4(                   \
        up8(af4[0][KSL]), up8(b4[KSL]), (KSL) == 0 ? fzero : acc0,            \
        4, 4, (KSL) & 3, ((KSL) >> 2) ? ascB0 : ascA0,                        \
              (KSL) & 3, ((KSL) >> 2) ? bscB : bscA);                         \
    acc1 = __builtin_amdgcn_mfma_scale_f32_32x32x64_f8f6f4(                   \
        up8(af4[1][KSL]), up8(b4[KSL]), (KSL) == 0 ? fzero : acc1,            \
        4, 4, (KSL) & 3, ((KSL) >> 2) ? ascB1 : ascA1,                        \
              (KSL) & 3, ((KSL) >> 2) ? bscB : bscA);                         \
    __builtin_amdgcn_s_setprio(0);                                            \
    b4[KSL] = *(const i32x4*)(gb + (size_t)(CHNEXT) * 8192 + (KSL) * 1024);

// One chunk: 16 MFMAs (2 independent 8-chains), then 32 fast-exp2 into accS.
#define CHUNK_STEP(CHNEXT)                                                    \
  {                                                                           \
    int nscA = *(const int*)(gsc + (size_t)(CHNEXT) * 512);                   \
    int nscB = *(const int*)(gsc + (size_t)(CHNEXT) * 512 + 4);               \
    KS_STEP(0, CHNEXT)                                                        \
    KS_STEP(1, CHNEXT)                                                        \
    KS_STEP(2, CHNEXT)                                                        \
    KS_STEP(3, CHNEXT)                                                        \
    KS_STEP(4, CHNEXT)                                                        \
    KS_STEP(5, CHNEXT)                                                        \
    KS_STEP(6, CHNEXT)                                                        \
    KS_STEP(7, CHNEXT)                                                        \
    _Pragma("unroll")                                                         \
    for (int i = 0; i < 16; ++i) {                                            \
      accS0[i] += __uint_as_float((unsigned)fmaf(acc0[i], 8388608.0f, FEC));  \
      accS1[i] += __uint_as_float((unsigned)fmaf(acc1[i], 8388608.0f, FEC));  \
    }                                                                         \
    bscA = nscA; bscB = nscB;                                                 \
  }

// Fused MX-fp4 32x32x64 GEMM, 2 A-tiles/wave (B-reuse 2, halved L2 traffic),
// barrier-free, 2 waves/SIMD.
__global__ __launch_bounds__(256, 2) void k_fused(
    const unsigned char* __restrict__ xn4, const unsigned char* __restrict__ xsc,
    const unsigned char* __restrict__ wt4, const unsigned char* __restrict__ wsc,
    float* __restrict__ pS) {
  const int tid = threadIdx.x;
  const int wv = tid >> 6, lane = tid & 63;
  const int h = lane >> 5, c = lane & 31;
  const int bid = blockIdx.x;
  const int logical = (bid & 7) * 64 + (bid >> 3);  // 512 = 8*64 XCD swizzle
  const int sp = logical >> 5;          // 0..15 (2 splits per XCD)
  const int rb = logical & 31;          // 0..31
  const int row0 = rb * BM + wv * 64;   // this wave's 64 rows (2 tiles of 32)

  // 2 A-tiles fully K-resident: af4[t][ks] = 16B at (row0+t*32+c)*256 + ks*32 + h*16.
  i32x4 af4[2][KS8];
  int ascA0, ascB0, ascA1, ascB1;
  {
    const unsigned char* x0 = xn4 + (size_t)(row0 + c) * 256 + h * 16;
    const unsigned char* x1 = xn4 + (size_t)(row0 + 32 + c) * 256 + h * 16;
    #pragma unroll
    for (int ks = 0; ks < KS8; ++ks) {
      af4[0][ks] = *(const i32x4*)(x0 + ks * 32);
      af4[1][ks] = *(const i32x4*)(x1 + ks * 32);
    }
    ascA0 = *(const int*)(xsc + (size_t)(row0 + c) * 16 + h * 8);
    ascB0 = *(const int*)(xsc + (size_t)(row0 + c) * 16 + h * 8 + 4);
    ascA1 = *(const int*)(xsc + (size_t)(row0 + 32 + c) * 16 + h * 8);
    ascB1 = *(const int*)(xsc + (size_t)(row0 + 32 + c) * 16 + h * 8 + 4);
  }

  float accS0[16], accS1[16];
  #pragma unroll
  for (int i = 0; i < 16; ++i) { accS0[i] = 0.0f; accS1[i] = 0.0f; }

  const f32x16 fzero = (f32x16)0.0f;

  const unsigned char* gb = wt4 + (size_t)(sp * GCH) * 8192 + lane * 16;
  const unsigned char* gsc = wsc + (size_t)(sp * GCH) * 512 + c * 16 + h * 8;

  i32x4 b4[KS8];
  #pragma unroll
  for (int ks = 0; ks < KS8; ++ks) b4[ks] = *(const i32x4*)(gb + ks * 1024);
  int bscA = *(const int*)gsc;
  int bscB = *(const int*)(gsc + 4);

  f32x16 acc0, acc1;

  for (int ch = 0; ch < GCH; ++ch) {
    int cn = ch + 1 < GCH ? ch + 1 : GCH - 1;
    CHUNK_STEP(cn)
  }

  // Sum over the 32 col-lanes (within each half); write per-(row,split) partials.
  #pragma unroll
  for (int i = 0; i < 16; ++i) {
    float S0 = accS0[i], S1 = accS1[i];
    #pragma unroll
    for (int m = 1; m <= 16; m <<= 1) {
      S0 += __shfl_xor(S0, m, 64);
      S1 += __shfl_xor(S1, m, 64);
    }
    accS0[i] = S0; accS1[i] = S1;
  }
  if (c == 0) {
    #pragma unroll
    for (int i = 0; i < 16; ++i) {
      int rl = (i & 3) + 8 * (i >> 2) + 4 * h;  // verified 32x32 C/D row map
      pS[(size_t)sp * N + row0 + rl] = accS0[i];
      pS[(size_t)sp * N + row0 + 32 + rl] = accS1[i];
    }
  }
}
#undef CHUNK_STEP
#undef KS_STEP

// Merge: S over splits; subtract exact pad contribution (256 cols x fastexp(0));
// x e^-16; swap plain label term for f32 margin term; NLL mean.
__global__ void k_merge(const float* __restrict__ pS, const float* __restrict__ coslab,
                        float* __restrict__ out) {
  int row = blockIdx.x * 256 + threadIdx.x;
  float S = 0.0f;
  #pragma unroll
  for (int s = 0; s < NSPLIT; ++s) S += pS[(size_t)s * N + row];
  S -= 256.0f * __uint_as_float((unsigned)FEC);  // exact pad-col correction
  float cl = coslab[row];
  float zp = SCL * cl;
  float ccl = fminf(fmaxf(cl, -1.0f + EPSC), 1.0f - EPSC);
  float zm = SCL * (ccl * COSM - sqrtf(1.0f - ccl * ccl) * SINM);
  float denom = S * EM16 - __expf(zp - SCL) + __expf(zm - SCL);
  float nll = SCL + logf(denom) - zm;
  #pragma unroll
  for (int m = 1; m <= 32; m <<= 1) nll += __shfl_xor(nll, m, 64);
  __shared__ float part[4];
  if ((threadIdx.x & 63) == 0) part[threadIdx.x >> 6] = nll;
  __syncthreads();
  if (threadIdx.x == 0)
    atomicAdd(out, (part[0] + part[1] + part[2] + part[3]) * (1.0f / N));
}

extern "C" void kernel_launch(void* const* d_in, const int* in_sizes, int n_in,
                              void* d_out, int out_size, void* d_ws, size_t ws_size,
                              hipStream_t stream) {
  const float* x = (const float*)d_in[0];
  const float* w = (const float*)d_in[1];
  const int* labels = (const int*)d_in[2];
  float* out = (float*)d_out;

  // ws: xn4 [N*256B] | xsc [N*16B] | wt4 [16*63*8KB] | wsc [16*63*512B]
  //   | pS f32 [NSPLIT*N] | coslab f32 [N]
  unsigned char* xn4 = (unsigned char*)d_ws;
  unsigned char* xsc = xn4 + (size_t)N * 256;
  unsigned char* wt4 = xsc + (size_t)N * 16;
  unsigned char* wsc = wt4 + (size_t)NSPLIT * GCH * 8192;
  float* pS = (float*)(wsc + (size_t)NSPLIT * GCH * 512);
  float* coslab = pS + (size_t)NSPLIT * N;

  hipLaunchKernelGGL(k_norm_x, dim3(N / 4), dim3(256), 0, stream,
                     x, (unsigned*)xn4, xsc, out);
  hipLaunchKernelGGL(k_normw_t, dim3(NSPLIT * GCH), dim3(256), 0, stream, w, wt4, wsc);
  hipLaunchKernelGGL(k_lab, dim3(N / 4), dim3(256), 0, stream, x, w, labels, coslab);
  hipLaunchKernelGGL(k_fused, dim3(32 * NSPLIT), dim3(256), 0, stream,
                     xn4, xsc, wt4, wsc, pS);
  hipLaunchKernelGGL(k_merge, dim3(N / 256), dim3(256), 0, stream, pS, coslab, out);
}

// Round 22
// 97.248 us; speedup vs baseline: 4.1396x; 1.0670x over previous
//
#include <hip/hip_runtime.h>

// ArcMarginLoss fused: normalize -> MX-fp4 MFMA GEMM + fixed-max softmax -> NLL mean.
// N=8192, D=512, C=32000, scale=16, margin=0.2.
// R22: R21 (L2-relief confirmed: 2 A-tiles/wave, 32x32x64 fp4) + (1) prep fusion:
// k_norm_x+k_lab+k_normw_t -> one k_prep (lab reuses x row regs; HBM streams
// overlap; 2 fewer launches), (2) k_fused pointer-bump refill addressing (no
// per-load cn*8192 math, no tail clamp; overrun prefetch lands in allocated ws,
// never consumed).

typedef __attribute__((ext_vector_type(4))) float f32x4;
typedef __attribute__((ext_vector_type(16))) float f32x16;
typedef __attribute__((ext_vector_type(4))) int i32x4;
typedef __attribute__((ext_vector_type(8))) int i32x8;

constexpr int N = 8192, D = 512, C = 32000;
constexpr int BM = 256;            // rows per block (4 waves x 2 tiles x 32 rows)
constexpr int NSPLIT = 16;         // column splits of C
constexpr int CPS = C / NSPLIT;    // 2000 real cols per split
constexpr int GCH = 63;            // padded chunks of 32 cols (2016) per split
constexpr int KS8 = 8;             // 8 k-steps of K=64
constexpr int XBLK = N / 4;        // 2048 prep blocks for x-norm+lab
constexpr float SCL = 16.0f;
constexpr float LOG2E = 1.4426950408889634f;
constexpr float S2 = SCL * LOG2E;              // folded into A pre-quant
constexpr float COSM = 0.98006657784124163f;  // cos(0.2)
constexpr float SINM = 0.19866933079506122f;  // sin(0.2)
constexpr float EPSC = 1e-7f;
constexpr float EM16 = 1.12535174719259114e-07f;  // exp(-16)
constexpr float FEC = 1064871712.0f;  // Schraudolph zero-mean magic (validated R12)

// fp4 e2m1 magnitude grid {0,.5,1,1.5,2,3,4,6} at codes 0..7.
__device__ __forceinline__ unsigned enc_fp4(float v, float inv) {
  unsigned s = (__float_as_uint(v) >> 31) << 3;
  float m = fabsf(v) * inv;
  float r = m < 2.0f ? 2.0f * m : (m < 4.0f ? m + 2.0f : fmaf(m, 0.5f, 4.0f));
  unsigned q = (unsigned)(r + 0.5f);
  return s | (q > 7u ? 7u : q);
}

// Per-32-block E8M0 scale from block absmax: smallest 2^e with absmax/2^e <= 6.
__device__ __forceinline__ void block_scale(float amax, unsigned& eB, float& inv) {
  unsigned u = __float_as_uint(amax * (1.0f / 6.0f));
  eB = (u >> 23) & 255u;
  if (u & 0x7fffffu) eB += 1u;      // ceil
  if (eB < 1u) eB = 1u;
  if (eB > 254u) eB = 254u;
  inv = __uint_as_float((254u - eB) << 23);  // 2^(127-eB)
}

__device__ __forceinline__ i32x8 up8(i32x4 v) {
  return __builtin_shufflevector(v, v, 0, 1, 2, 3, -1, -1, -1, -1);  // upper undef
}

// Fused prep: blocks [0,XBLK): x-norm (fp4 quant) + label-cosine (reuses x row
// registers). Blocks [XBLK, XBLK+16*GCH): w-norm into transposed fp4 chunk
// images + scale images (pad cols -> zeros).
__global__ void k_prep(const float* __restrict__ x, const float* __restrict__ w,
                       const int* __restrict__ labels,
                       unsigned* __restrict__ xn4, unsigned char* __restrict__ xsc,
                       unsigned char* __restrict__ wt4, unsigned char* __restrict__ wsc,
                       float* __restrict__ coslab, float* __restrict__ outz) {
  __shared__ unsigned lbuf[2048];         // 8KB chunk image (w path only)
  __shared__ unsigned char sbuf[512];     // scale image (w path only)
  const int tid = threadIdx.x, wv = tid >> 6, L = tid & 63;
  if (blockIdx.x == 0 && tid == 0) *outz = 0.0f;

  if (blockIdx.x < XBLK) {
    // ---- x-norm + lab: 4 rows per block, one wave per row ----
    int r = (blockIdx.x << 2) + wv;
    const float* row = x + (size_t)r * D;
    float f[8];
    *(f32x4*)&f[0] = *(const f32x4*)(row + L * 8);
    *(f32x4*)&f[4] = *(const f32x4*)(row + L * 8 + 4);
    float ss = 0.f;
    #pragma unroll
    for (int i = 0; i < 8; ++i) ss += f[i] * f[i];
    // lab: load w[labels[r]] row, dot + norm alongside x's sum-square.
    const float* wr = w + (size_t)labels[r] * D;
    float p[8];
    *(f32x4*)&p[0] = *(const f32x4*)(wr + L * 8);
    *(f32x4*)&p[4] = *(const f32x4*)(wr + L * 8 + 4);
    float ww = 0.f, xw = 0.f;
    #pragma unroll
    for (int i = 0; i < 8; ++i) { ww += p[i] * p[i]; xw += f[i] * p[i]; }
    #pragma unroll
    for (int m = 1; m <= 32; m <<= 1) {
      ss += __shfl_xor(ss, m, 64);
      ww += __shfl_xor(ww, m, 64);
      xw += __shfl_xor(xw, m, 64);
    }
    if (L == 0)
      coslab[r] = xw / (fmaxf(sqrtf(ss), 1e-12f) * fmaxf(sqrtf(ww), 1e-12f));
    // x-norm quantize: v = x_hat * S2; per-32-block scale (quad absmax).
    float sc = S2 / fmaxf(sqrtf(ss), 1e-12f);
    float v[8], am = 0.f;
    #pragma unroll
    for (int i = 0; i < 8; ++i) { v[i] = f[i] * sc; am = fmaxf(am, fabsf(v[i])); }
    am = fmaxf(am, __shfl_xor(am, 1, 64));
    am = fmaxf(am, __shfl_xor(am, 2, 64));
    unsigned eB; float inv;
    block_scale(am, eB, inv);
    unsigned pk = 0;
    #pragma unroll
    for (int j = 0; j < 8; ++j) pk |= enc_fp4(v[j], inv) << (4 * j);
    xn4[(size_t)r * 64 + L] = pk;
    if ((L & 3) == 0) {
      int kb = L >> 2;  // k-block 0..15; kb = 2*ks + h
      xsc[(size_t)r * 16 + (kb & 1) * 8 + (kb >> 1)] = (unsigned char)eB;
    }
    return;
  }

  // ---- w-norm transpose: one block per padded 32-col chunk ----
  const int gidx = blockIdx.x - XBLK;
  const int sp = gidx / GCH, within = gidx % GCH;
  #pragma unroll
  for (int t = 0; t < 8; ++t) {
    int rl = t * 4 + wv;  // 0..31 (col within chunk)
    int colin = within * 32 + rl;
    bool valid = colin < CPS;             // wave-uniform
    unsigned pk = 0;
    unsigned eB = 1u;
    if (valid) {
      const float* row = w + ((size_t)sp * CPS + colin) * D;
      float f[8];
      *(f32x4*)&f[0] = *(const f32x4*)(row + L * 8);
      *(f32x4*)&f[4] = *(const f32x4*)(row + L * 8 + 4);
      float ss = 0.f;
      #pragma unroll
      for (int i = 0; i < 8; ++i) ss += f[i] * f[i];
      #pragma unroll
      for (int m = 1; m <= 32; m <<= 1) ss += __shfl_xor(ss, m, 64);
      float sc = 1.0f / fmaxf(sqrtf(ss), 1e-12f);
      float v[8], am = 0.f;
      #pragma unroll
      for (int i = 0; i < 8; ++i) { v[i] = f[i] * sc; am = fmaxf(am, fabsf(v[i])); }
      am = fmaxf(am, __shfl_xor(am, 1, 64));
      am = fmaxf(am, __shfl_xor(am, 2, 64));
      float inv;
      block_scale(am, eB, inv);
      #pragma unroll
      for (int j = 0; j < 8; ++j) pk |= enc_fp4(v[j], inv) << (4 * j);
    }
    // lane L covers k=8L..8L+8: ks=L>>3, h=(L>>2)&1, dword slot (L&3)
    lbuf[(L >> 3) * 256 + (((L >> 2) & 1) * 32 + rl) * 4 + (L & 3)] = pk;
    if ((L & 3) == 0) {
      int kb = L >> 2;
      sbuf[rl * 16 + (kb & 1) * 8 + (kb >> 1)] = (unsigned char)eB;
    }
  }
  __syncthreads();
  uint4* dst = (uint4*)(wt4 + (size_t)gidx * 8192);
  #pragma unroll
  for (int i = 0; i < 2; ++i) dst[i * 256 + tid] = ((const uint4*)lbuf)[i * 256 + tid];
  if (tid < 128)
    ((unsigned*)(wsc + (size_t)gidx * 512))[tid] = ((const unsigned*)sbuf)[tid];
}

// One k-step with LITERAL ks 0..7 (opsel immediates: word KSL>>2, byte KSL&3).
// TWO MFMAs (tiles 0,1) share b4[KSL]. ks=0 seeds from fzero. Refill from the
// next-chunk pointer pnx (bumped once per chunk; immediate offsets only).
#define KS_STEP(KSL)                                                          \
    __builtin_amdgcn_s_setprio(1);                                            \
    acc0 = __builtin_amdgcn_mfma_scale_f32_32x32x64_f8f6f4(                   \
        up8(af4[0][KSL]), up8(b4[KSL]), (KSL) == 0 ? fzero : acc0,            \
        4, 4, (KSL) & 3, ((KSL) >> 2) ? ascB0 : ascA0,                        \
              (KSL) & 3, ((KSL) >> 2) ? bscB : bscA);                         \
    acc1 = __builtin_amdgcn_mfma_scale_f32_32x32x64_f8f6f4(                   \
        up8(af4[1][KSL]), up8(b4[KSL]), (KSL) == 0 ? fzero : acc1,            \
        4, 4, (KSL) & 3, ((KSL) >> 2) ? ascB1 : ascA1,                        \
              (KSL) & 3, ((KSL) >> 2) ? bscB : bscA);                         \
    __builtin_amdgcn_s_setprio(0);                                            \
    b4[KSL] = *(const i32x4*)(pnx + (KSL) * 1024);

// One chunk: 16 MFMAs (2 independent 8-chains), then 32 fast-exp2 into accS.
// Scale words for the next chunk prefetched from gscn; pointers bumped once.
#define CHUNK_STEP                                                            \
  {                                                                           \
    int nscA = *(const int*)gscn;                                             \
    int nscB = *(const int*)(gscn + 4);                                       \
    KS_STEP(0)                                                                \
    KS_STEP(1)                                                                \
    KS_STEP(2)                                                                \
    KS_STEP(3)                                                                \
    KS_STEP(4)                                                                \
    KS_STEP(5)                                                                \
    KS_STEP(6)                                                                \
    KS_STEP(7)                                                                \
    _Pragma("unroll")                                                         \
    for (int i = 0; i < 16; ++i) {                                            \
      accS0[i] += __uint_as_float((unsigned)fmaf(acc0[i], 8388608.0f, FEC));  \
      accS1[i] += __uint_as_float((unsigned)fmaf(acc1[i], 8388608.0f, FEC));  \
    }                                                                         \
    bscA = nscA; bscB = nscB;                                                 \
    pnx += 8192; gscn += 512;                                                 \
  }

// Fused MX-fp4 32x32x64 GEMM, 2 A-tiles/wave (B-reuse 2, halved L2 traffic),
// barrier-free, 2 waves/SIMD, pointer-bump refill addressing.
__global__ __launch_bounds__(256, 2) void k_fused(
    const unsigned char* __restrict__ xn4, const unsigned char* __restrict__ xsc,
    const unsigned char* __restrict__ wt4, const unsigned char* __restrict__ wsc,
    float* __restrict__ pS) {
  const int tid = threadIdx.x;
  const int wv = tid >> 6, lane = tid & 63;
  const int h = lane >> 5, c = lane & 31;
  const int bid = blockIdx.x;
  const int logical = (bid & 7) * 64 + (bid >> 3);  // 512 = 8*64 XCD swizzle
  const int sp = logical >> 5;          // 0..15 (2 splits per XCD)
  const int rb = logical & 31;          // 0..31
  const int row0 = rb * BM + wv * 64;   // this wave's 64 rows (2 tiles of 32)

  // 2 A-tiles fully K-resident: af4[t][ks] = 16B at (row0+t*32+c)*256 + ks*32 + h*16.
  i32x4 af4[2][KS8];
  int ascA0, ascB0, ascA1, ascB1;
  {
    const unsigned char* x0 = xn4 + (size_t)(row0 + c) * 256 + h * 16;
    const unsigned char* x1 = xn4 + (size_t)(row0 + 32 + c) * 256 + h * 16;
    #pragma unroll
    for (int ks = 0; ks < KS8; ++ks) {
      af4[0][ks] = *(const i32x4*)(x0 + ks * 32);
      af4[1][ks] = *(const i32x4*)(x1 + ks * 32);
    }
    ascA0 = *(const int*)(xsc + (size_t)(row0 + c) * 16 + h * 8);
    ascB0 = *(const int*)(xsc + (size_t)(row0 + c) * 16 + h * 8 + 4);
    ascA1 = *(const int*)(xsc + (size_t)(row0 + 32 + c) * 16 + h * 8);
    ascB1 = *(const int*)(xsc + (size_t)(row0 + 32 + c) * 16 + h * 8 + 4);
  }

  float accS0[16], accS1[16];
  #pragma unroll
  for (int i = 0; i < 16; ++i) { accS0[i] = 0.0f; accS1[i] = 0.0f; }

  const f32x16 fzero = (f32x16)0.0f;

  const unsigned char* gb = wt4 + (size_t)(sp * GCH) * 8192 + lane * 16;
  const unsigned char* gscn = wsc + (size_t)(sp * GCH) * 512 + c * 16 + h * 8;

  i32x4 b4[KS8];
  #pragma unroll
  for (int ks = 0; ks < KS8; ++ks) b4[ks] = *(const i32x4*)(gb + ks * 1024);
  int bscA = *(const int*)gscn;
  int bscB = *(const int*)(gscn + 4);
  const unsigned char* pnx = gb + 8192;  // next-chunk load pointer
  gscn += 512;                           // next-chunk scale pointer

  f32x16 acc0, acc1;

  // Final iteration's refill reads one-past-split (allocated ws; unused).
  for (int ch = 0; ch < GCH; ++ch) {
    CHUNK_STEP
  }

  // Sum over the 32 col-lanes (within each half); write per-(row,split) partials.
  #pragma unroll
  for (int i = 0; i < 16; ++i) {
    float S0 = accS0[i], S1 = accS1[i];
    #pragma unroll
    for (int m = 1; m <= 16; m <<= 1) {
      S0 += __shfl_xor(S0, m, 64);
      S1 += __shfl_xor(S1, m, 64);
    }
    accS0[i] = S0; accS1[i] = S1;
  }
  if (c == 0) {
    #pragma unroll
    for (int i = 0; i < 16; ++i) {
      int rl = (i & 3) + 8 * (i >> 2) + 4 * h;  // verified 32x32 C/D row map
      pS[(size_t)sp * N + row0 + rl] = accS0[i];
      pS[(size_t)sp * N + row0 + 32 + rl] = accS1[i];
    }
  }
}
#undef CHUNK_STEP
#undef KS_STEP

// Merge: S over splits; subtract exact pad contribution (256 cols x fastexp(0));
// x e^-16; swap plain label term for f32 margin term; NLL mean.
__global__ void k_merge(const float* __restrict__ pS, const float* __restrict__ coslab,
                        float* __restrict__ out) {
  int row = blockIdx.x * 256 + threadIdx.x;
  float S = 0.0f;
  #pragma unroll
  for (int s = 0; s < NSPLIT; ++s) S += pS[(size_t)s * N + row];
  S -= 256.0f * __uint_as_float((unsigned)FEC);  // exact pad-col correction
  float cl = coslab[row];
  float zp = SCL * cl;
  float ccl = fminf(fmaxf(cl, -1.0f + EPSC), 1.0f - EPSC);
  float zm = SCL * (ccl * COSM - sqrtf(1.0f - ccl * ccl) * SINM);
  float denom = S * EM16 - __expf(zp - SCL) + __expf(zm - SCL);
  float nll = SCL + logf(denom) - zm;
  #pragma unroll
  for (int m = 1; m <= 32; m <<= 1) nll += __shfl_xor(nll, m, 64);
  __shared__ float part[4];
  if ((threadIdx.x & 63) == 0) part[threadIdx.x >> 6] = nll;
  __syncthreads();
  if (threadIdx.x == 0)
    atomicAdd(out, (part[0] + part[1] + part[2] + part[3]) * (1.0f / N));
}

extern "C" void kernel_launch(void* const* d_in, const int* in_sizes, int n_in,
                              void* d_out, int out_size, void* d_ws, size_t ws_size,
                              hipStream_t stream) {
  const float* x = (const float*)d_in[0];
  const float* w = (const float*)d_in[1];
  const int* labels = (const int*)d_in[2];
  float* out = (float*)d_out;

  // ws: xn4 [N*256B] | xsc [N*16B] | wt4 [16*63*8KB] | wsc [16*63*512B]
  //   | pS f32 [NSPLIT*N] | coslab f32 [N]
  unsigned char* xn4 = (unsigned char*)d_ws;
  unsigned char* xsc = xn4 + (size_t)N * 256;
  unsigned char* wt4 = xsc + (size_t)N * 16;
  unsigned char* wsc = wt4 + (size_t)NSPLIT * GCH * 8192;
  float* pS = (float*)(wsc + (size_t)NSPLIT * GCH * 512);
  float* coslab = pS + (size_t)NSPLIT * N;

  hipLaunchKernelGGL(k_prep, dim3(XBLK + NSPLIT * GCH), dim3(256), 0, stream,
                     x, w, labels, (unsigned*)xn4, xsc, wt4, wsc, coslab, out);
  hipLaunchKernelGGL(k_fused, dim3(32 * NSPLIT), dim3(256), 0, stream,
                     xn4, xsc, wt4, wsc, pS);
  hipLaunchKernelGGL(k_merge, dim3(N / 256), dim3(256), 0, stream, pS, coslab, out);
}